// Round 2
// baseline (581.203 us; speedup 1.0000x reference)
//
#include <hip/hip_runtime.h>
#include <math.h>

#define D 128

__device__ __forceinline__ float sigmoidf_(float x) { return 1.f / (1.f + __expf(-x)); }

// ---------------- segment bounds: seg_off[g] = lower_bound(index, g) ----------------
// NOTE: harness delivers integer inputs as int32 (not the reference's int64).
__global__ void seg_bounds_kernel(const int* __restrict__ idx, int N, int G,
                                  int* __restrict__ seg_off) {
    int g = blockIdx.x * blockDim.x + threadIdx.x;
    if (g > G) return;
    int lo = 0, hi = N;
    while (lo < hi) {
        int mid = (lo + hi) >> 1;
        if (idx[mid] < g) lo = mid + 1; else hi = mid;
    }
    seg_off[g] = lo;
}

// ---------------- Wc = W_ih[:, :D] + W_hh  (both [512, D] row-major result) --------
__global__ void prep_wc_kernel(const float* __restrict__ W_ih, const float* __restrict__ W_hh,
                               float* __restrict__ Wc) {
    int t = blockIdx.x * blockDim.x + threadIdx.x;
    if (t >= 4 * D * D) return;
    int j = t >> 7;           // row (gate index 0..511)
    int k = t & (D - 1);      // col
    Wc[t] = W_ih[(size_t)j * (2 * D) + k] + W_hh[t];
}

// ---------------- b_sum = b_ih + b_hh; h1/c1 from biases only (step 1 is constant) --
__global__ void prep_bias_kernel(const float* __restrict__ b_ih, const float* __restrict__ b_hh,
                                 float* __restrict__ b_sum, float* __restrict__ h1,
                                 float* __restrict__ c1) {
    int t = threadIdx.x;  // 512 threads, 1 block
    float b = b_ih[t] + b_hh[t];
    b_sum[t] = b;
    if (t < D) {
        float bi = b_ih[t] + b_hh[t];
        float bg = b_ih[2 * D + t] + b_hh[2 * D + t];
        float bo = b_ih[3 * D + t] + b_hh[3 * D + t];
        float c = sigmoidf_(bi) * tanhf(bg);   // c0 = 0 so f-gate term vanishes
        c1[t] = c;
        h1[t] = sigmoidf_(bo) * tanhf(c);
    }
}

// ---------------- base2[j] = b_sum[j] + dot(h1, Wc[j,:])  (step-2 constant part) ----
__global__ void base2_kernel(const float* __restrict__ Wc, const float* __restrict__ b_sum,
                             const float* __restrict__ h1, float* __restrict__ base2) {
    __shared__ float hs[D];
    int j = blockIdx.x * 256 + threadIdx.x;   // 2 blocks x 256 -> j in [0,512)
    if (threadIdx.x < D) hs[threadIdx.x] = h1[threadIdx.x];
    __syncthreads();
    float acc = 0.f;
    const float4* w4 = (const float4*)(Wc + (size_t)j * D);
#pragma unroll 8
    for (int k4 = 0; k4 < D / 4; ++k4) {
        float4 w = w4[k4];
        const float* hp = &hs[k4 * 4];
        acc += w.x * hp[0] + w.y * hp[1] + w.z * hp[2] + w.w * hp[3];
    }
    base2[j] = b_sum[j] + acc;
}

// ---------------- attention with online softmax: one wave per segment ----------------
// e_n = dot(x_n, q_g); r_g = sum softmax(e) * x_n   (single pass over segment rows)
__global__ __launch_bounds__(64) void attn_kernel(
    const float* __restrict__ x,       // [N, D]
    const int* __restrict__ seg_off,   // [G+1]
    const float* __restrict__ q,       // row per segment (stride) or broadcast (stride 0)
    int q_stride,
    float* __restrict__ r_out, int r_stride,
    int G) {
    int g = blockIdx.x;
    if (g >= G) return;
    int lane = threadIdx.x;
    const float2* x2 = (const float2*)x;
    const float2* q2 = (const float2*)(q + (size_t)g * q_stride);
    float2 qv = q2[lane];
    int start = seg_off[g], end = seg_off[g + 1];

    float m = -INFINITY, s = 0.f;
    float2 acc; acc.x = 0.f; acc.y = 0.f;

    int n = start;
    for (; n + 2 <= end; n += 2) {
        float2 x0 = x2[(size_t)n * 64 + lane];
        float2 x1 = x2[(size_t)(n + 1) * 64 + lane];
        float p0 = x0.x * qv.x + x0.y * qv.y;
        float p1 = x1.x * qv.x + x1.y * qv.y;
#pragma unroll
        for (int off = 1; off < 64; off <<= 1) {
            p0 += __shfl_xor(p0, off);
            p1 += __shfl_xor(p1, off);
        }
        float mn = fmaxf(m, fmaxf(p0, p1));
        float al = __expf(m - mn);       // m = -inf on first iter -> al = 0
        float w0 = __expf(p0 - mn);
        float w1 = __expf(p1 - mn);
        s = s * al + w0 + w1;
        acc.x = acc.x * al + w0 * x0.x + w1 * x1.x;
        acc.y = acc.y * al + w0 * x0.y + w1 * x1.y;
        m = mn;
    }
    if (n < end) {
        float2 x0 = x2[(size_t)n * 64 + lane];
        float p0 = x0.x * qv.x + x0.y * qv.y;
#pragma unroll
        for (int off = 1; off < 64; off <<= 1) p0 += __shfl_xor(p0, off);
        float mn = fmaxf(m, p0);
        float al = __expf(m - mn);
        float w0 = __expf(p0 - mn);
        s = s * al + w0;
        acc.x = acc.x * al + w0 * x0.x;
        acc.y = acc.y * al + w0 * x0.y;
    }
    float inv = 1.f / fmaxf(s, 1e-16f);   // empty segment -> acc=0 -> r=0 (matches ref)
    float2 r; r.x = acc.x * inv; r.y = acc.y * inv;
    *(float2*)&r_out[(size_t)g * r_stride + 2 * lane] = r;
}

// ---------------- gates GEMM: gates[g,j] = bias[j] + A1[g,:]·W1[j,:] + A2[g,:]·W2[j,:]
// Tile 128x128, micro-tile 8x8 per thread, KC=16, fp32 VALU (no fp32 MFMA on CDNA4).
__global__ __launch_bounds__(256) void gates_gemm_kernel(
    const float* __restrict__ A1,   // [G, D] stride D, or nullptr to skip phase 0
    const float* __restrict__ W1,   // [512, D] stride D (Wc)
    const float* __restrict__ A2,   // [G, D] stride D
    const float* __restrict__ W2,   // [512, .] stride sW2 (W_ih + D, stride 2D)
    int sW2,
    const float* __restrict__ bias, // [512]
    float* __restrict__ gates) {    // [G, 512]
    __shared__ float As[16][132];   // [k][row], padded row stride (16B-aligned, conflict-safe)
    __shared__ float Ws[16][132];
    int t = threadIdx.x;
    int tx = t & 15, ty = t >> 4;
    int g0 = blockIdx.x * 128, j0 = blockIdx.y * 128;
    int lr = t >> 1;           // 0..127: row of the tile this thread stages
    int lk = (t & 1) * 8;      // 0 or 8: k-offset this thread stages

    float acc[8][8];
#pragma unroll
    for (int i = 0; i < 8; ++i)
#pragma unroll
        for (int j = 0; j < 8; ++j) acc[i][j] = 0.f;

    for (int phase = 0; phase < 2; ++phase) {
        const float* A = phase ? A2 : A1;
        if (A == nullptr) continue;
        const float* W = phase ? W2 : W1;
        int sW = phase ? sW2 : D;
        for (int kk = 0; kk < D; kk += 16) {
            float4 a0 = *(const float4*)&A[(size_t)(g0 + lr) * D + kk + lk];
            float4 a1 = *(const float4*)&A[(size_t)(g0 + lr) * D + kk + lk + 4];
            float4 w0 = *(const float4*)&W[(size_t)(j0 + lr) * sW + kk + lk];
            float4 w1 = *(const float4*)&W[(size_t)(j0 + lr) * sW + kk + lk + 4];
            __syncthreads();
            As[lk + 0][lr] = a0.x; As[lk + 1][lr] = a0.y; As[lk + 2][lr] = a0.z; As[lk + 3][lr] = a0.w;
            As[lk + 4][lr] = a1.x; As[lk + 5][lr] = a1.y; As[lk + 6][lr] = a1.z; As[lk + 7][lr] = a1.w;
            Ws[lk + 0][lr] = w0.x; Ws[lk + 1][lr] = w0.y; Ws[lk + 2][lr] = w0.z; Ws[lk + 3][lr] = w0.w;
            Ws[lk + 4][lr] = w1.x; Ws[lk + 5][lr] = w1.y; Ws[lk + 6][lr] = w1.z; Ws[lk + 7][lr] = w1.w;
            __syncthreads();
#pragma unroll
            for (int k = 0; k < 16; ++k) {
                float4 a0v = *(const float4*)&As[k][ty * 8];
                float4 a1v = *(const float4*)&As[k][ty * 8 + 4];
                float4 b0v = *(const float4*)&Ws[k][tx * 8];
                float4 b1v = *(const float4*)&Ws[k][tx * 8 + 4];
                float av[8] = {a0v.x, a0v.y, a0v.z, a0v.w, a1v.x, a1v.y, a1v.z, a1v.w};
                float bv[8] = {b0v.x, b0v.y, b0v.z, b0v.w, b1v.x, b1v.y, b1v.z, b1v.w};
#pragma unroll
                for (int i = 0; i < 8; ++i)
#pragma unroll
                    for (int j = 0; j < 8; ++j)
                        acc[i][j] = fmaf(av[i], bv[j], acc[i][j]);
            }
        }
    }
    // epilogue: add bias, store
#pragma unroll
    for (int i = 0; i < 8; ++i) {
        size_t row = (size_t)(g0 + ty * 8 + i);
        float4 o0, o1;
        int jb = j0 + tx * 8;
        o0.x = acc[i][0] + bias[jb + 0]; o0.y = acc[i][1] + bias[jb + 1];
        o0.z = acc[i][2] + bias[jb + 2]; o0.w = acc[i][3] + bias[jb + 3];
        o1.x = acc[i][4] + bias[jb + 4]; o1.y = acc[i][5] + bias[jb + 5];
        o1.z = acc[i][6] + bias[jb + 6]; o1.w = acc[i][7] + bias[jb + 7];
        *(float4*)&gates[row * 512 + jb] = o0;
        *(float4*)&gates[row * 512 + jb + 4] = o1;
    }
}

// ---------------- LSTM cell elementwise: c,h from gates ----------------
__global__ void cell_kernel(const float* __restrict__ gates,   // [G, 512]
                            const float* __restrict__ c_prev, int c_stride,  // 0 => broadcast row
                            float* __restrict__ c_out,          // [G, D]
                            float* __restrict__ h_out, int h_stride,
                            int total) {                        // G*D
    int t = blockIdx.x * blockDim.x + threadIdx.x;
    if (t >= total) return;
    int g = t >> 7, k = t & (D - 1);
    const float* grow = gates + (size_t)g * 512;
    float ig = grow[k];
    float fg = grow[D + k];
    float gg = grow[2 * D + k];
    float og = grow[3 * D + k];
    float cp = c_prev[(size_t)g * c_stride + k];
    float c = sigmoidf_(fg) * cp + sigmoidf_(ig) * tanhf(gg);
    float h = sigmoidf_(og) * tanhf(c);
    c_out[t] = c;
    h_out[(size_t)g * h_stride + k] = h;
}

extern "C" void kernel_launch(void* const* d_in, const int* in_sizes, int n_in,
                              void* d_out, int out_size, void* d_ws, size_t ws_size,
                              hipStream_t stream) {
    const float* x      = (const float*)d_in[0];
    const float* W_ih   = (const float*)d_in[1];
    const float* W_hh   = (const float*)d_in[2];
    const float* b_ih   = (const float*)d_in[3];
    const float* b_hh   = (const float*)d_in[4];
    const int*   index  = (const int*)d_in[5];   // harness delivers integers as int32
    int N = in_sizes[5];
    int G = out_size / (2 * D);      // 4096
    float* out = (float*)d_out;

    // workspace layout (floats) — ~17 MB total
    float* ws = (float*)d_ws;
    float* Wc     = ws;                         // 512*D
    float* b_sum  = Wc + 4 * D * D;             // 512
    float* h1     = b_sum + 4 * D;              // D
    float* c1     = h1 + D;                     // D
    float* base2  = c1 + D;                     // 512
    float* r1     = base2 + 4 * D;              // G*D
    float* h2     = r1 + (size_t)G * D;         // G*D
    float* c2     = h2 + (size_t)G * D;         // G*D
    float* r2     = c2 + (size_t)G * D;         // G*D
    float* gatesb = r2 + (size_t)G * D;         // G*4D
    int* seg_off  = (int*)(gatesb + (size_t)G * 4 * D);  // G+1 ints
    float* c3     = r1;  // r1 is dead after the step-3 GEMM; c3 is never read (last step)

    // prep (independent of steps)
    seg_bounds_kernel<<<(G + 1 + 255) / 256, 256, 0, stream>>>(index, N, G, seg_off);
    prep_wc_kernel<<<(4 * D * D + 255) / 256, 256, 0, stream>>>(W_ih, W_hh, Wc);
    prep_bias_kernel<<<1, 512, 0, stream>>>(b_ih, b_hh, b_sum, h1, c1);
    base2_kernel<<<2, 256, 0, stream>>>(Wc, b_sum, h1, base2);

    // ---- step 1: h1/c1 constant row; attention with broadcast q = h1
    attn_kernel<<<G, 64, 0, stream>>>(x, seg_off, h1, 0, r1, D, G);

    // ---- step 2: gates = base2 + r1 @ Wr^T ; cell with broadcast c1
    gates_gemm_kernel<<<dim3(G / 128, 4), 256, 0, stream>>>(
        nullptr, Wc, r1, W_ih + D, 2 * D, base2, gatesb);
    cell_kernel<<<(G * D + 255) / 256, 256, 0, stream>>>(gatesb, c1, 0, c2, h2, D, G * D);
    attn_kernel<<<G, 64, 0, stream>>>(x, seg_off, h2, D, r2, D, G);

    // ---- step 3: gates = b_sum + h2 @ Wc^T + r2 @ Wr^T ; h3 goes straight into out[:, :D]
    gates_gemm_kernel<<<dim3(G / 128, 4), 256, 0, stream>>>(
        h2, Wc, r2, W_ih + D, 2 * D, b_sum, gatesb);
    cell_kernel<<<(G * D + 255) / 256, 256, 0, stream>>>(gatesb, c2, D, c3, out, 2 * D, G * D);
    // final attention: q = h3 (in out, stride 2D), r3 -> out[:, D:] (stride 2D)
    attn_kernel<<<G, 64, 0, stream>>>(x, seg_off, out, 2 * D, out + D, 2 * D, G);
}

// Round 3
// 529.552 us; speedup vs baseline: 1.0975x; 1.0975x over previous
//
#include <hip/hip_runtime.h>
#include <math.h>

#define D 128

__device__ __forceinline__ float sigmoidf_(float x) { return 1.f / (1.f + __expf(-x)); }

// ---------------- segment bounds: seg_off[g] = lower_bound(index, g) ----------------
// NOTE: harness delivers integer inputs as int32.
__global__ void seg_bounds_kernel(const int* __restrict__ idx, int N, int G,
                                  int* __restrict__ seg_off) {
    int g = blockIdx.x * blockDim.x + threadIdx.x;
    if (g > G) return;
    int lo = 0, hi = N;
    while (lo < hi) {
        int mid = (lo + hi) >> 1;
        if (idx[mid] < g) lo = mid + 1; else hi = mid;
    }
    seg_off[g] = lo;
}

// ---------------- Wc = W_ih[:, :D] + W_hh  ([512, D] row-major) --------
__global__ void prep_wc_kernel(const float* __restrict__ W_ih, const float* __restrict__ W_hh,
                               float* __restrict__ Wc) {
    int t = blockIdx.x * blockDim.x + threadIdx.x;
    if (t >= 4 * D * D) return;
    int j = t >> 7;
    int k = t & (D - 1);
    Wc[t] = W_ih[(size_t)j * (2 * D) + k] + W_hh[t];
}

// ---------------- b_sum = b_ih + b_hh; h1/c1 from biases only ----------------
__global__ void prep_bias_kernel(const float* __restrict__ b_ih, const float* __restrict__ b_hh,
                                 float* __restrict__ b_sum, float* __restrict__ h1,
                                 float* __restrict__ c1) {
    int t = threadIdx.x;  // 512 threads, 1 block
    float b = b_ih[t] + b_hh[t];
    b_sum[t] = b;
    if (t < D) {
        float bi = b_ih[t] + b_hh[t];
        float bg = b_ih[2 * D + t] + b_hh[2 * D + t];
        float bo = b_ih[3 * D + t] + b_hh[3 * D + t];
        float c = sigmoidf_(bi) * tanhf(bg);
        c1[t] = c;
        h1[t] = sigmoidf_(bo) * tanhf(c);
    }
}

// ---------------- base2[j] = b_sum[j] + dot(h1, Wc[j,:]) ----------------
__global__ void base2_kernel(const float* __restrict__ Wc, const float* __restrict__ b_sum,
                             const float* __restrict__ h1, float* __restrict__ base2) {
    __shared__ float hs[D];
    int j = blockIdx.x * 256 + threadIdx.x;
    if (threadIdx.x < D) hs[threadIdx.x] = h1[threadIdx.x];
    __syncthreads();
    float acc = 0.f;
    const float4* w4 = (const float4*)(Wc + (size_t)j * D);
#pragma unroll 8
    for (int k4 = 0; k4 < D / 4; ++k4) {
        float4 w = w4[k4];
        const float* hp = &hs[k4 * 4];
        acc += w.x * hp[0] + w.y * hp[1] + w.z * hp[2] + w.w * hp[3];
    }
    base2[j] = b_sum[j] + acc;
}

// ---------------- attention v2: 4 waves per segment, online softmax ----------------
// Each wave: lanes 0-31 = row n, lanes 32-63 = row n+1; float4/lane (1 KB coalesced load).
// Reduce: 5-step butterfly within 32-lane half + one xor-32 exchange (6 shuffles / 2 rows).
// Per-wave (m, s, acc) merged through LDS at the end.
__global__ __launch_bounds__(256) void attn_kernel(
    const float* __restrict__ x,       // [N, D]
    const int* __restrict__ seg_off,   // [G+1]
    const float* __restrict__ q,       // [G, q_stride] or broadcast (stride 0)
    int q_stride,
    float* __restrict__ r_out, int r_stride,
    int G) {
    int g = blockIdx.x;
    if (g >= G) return;
    int tid = threadIdx.x;
    int wave = tid >> 6, lane = tid & 63;
    int half = lane >> 5;        // 0: even row of pair, 1: odd row
    int col4 = lane & 31;        // float4 chunk index (covers cols col4*4 .. +3)

    __shared__ float sm[4], ss[4];
    __shared__ float sacc[4][D];

    int start = seg_off[g], end = seg_off[g + 1];
    int count = end - start;
    int chunk = (count + 3) >> 2;
    int wsr = start + wave * chunk;
    int wer = min(wsr + chunk, end);

    const float4* x4 = (const float4*)x;   // row stride = 32 float4
    const float4* q4 = (const float4*)(q + (size_t)g * q_stride);
    float4 qv = q4[col4];

    float m = -INFINITY, s = 0.f;
    float4 acc = {0.f, 0.f, 0.f, 0.f};

    if (wsr < wer) {
        int r0 = wsr + half; r0 = r0 < wer ? r0 : wer - 1;
        float4 xv = x4[(size_t)r0 * 32 + col4];
        for (int n = wsr; n < wer; n += 2) {
            // prefetch next pair (clamped; one redundant load on last iter)
            int r2 = n + 2 + half; r2 = r2 < wer ? r2 : wer - 1;
            float4 xn = x4[(size_t)r2 * 32 + col4];

            float p = xv.x * qv.x + xv.y * qv.y + xv.z * qv.z + xv.w * qv.w;
            p += __shfl_xor(p, 1);
            p += __shfl_xor(p, 2);
            p += __shfl_xor(p, 4);
            p += __shfl_xor(p, 8);
            p += __shfl_xor(p, 16);
            float po = __shfl_xor(p, 32);
            float p0 = half ? po : p;
            float p1 = half ? p : po;
            if (n + 1 >= wer) p1 = -INFINITY;   // odd tail: second row is a dummy

            float mn = fmaxf(m, fmaxf(p0, p1));
            float al = __expf(m - mn);           // first iter: exp(-inf) = 0
            float w0 = __expf(p0 - mn);
            float w1 = __expf(p1 - mn);          // dummy row -> 0
            float wsel = half ? w1 : w0;
            s = s * al + w0 + w1;
            acc.x = acc.x * al + wsel * xv.x;
            acc.y = acc.y * al + wsel * xv.y;
            acc.z = acc.z * al + wsel * xv.z;
            acc.w = acc.w * al + wsel * xv.w;
            m = mn;
            xv = xn;
        }
    }
    // merge the two 32-lane halves of this wave's accumulator
    acc.x += __shfl_xor(acc.x, 32);
    acc.y += __shfl_xor(acc.y, 32);
    acc.z += __shfl_xor(acc.z, 32);
    acc.w += __shfl_xor(acc.w, 32);

    if (lane == 0) { sm[wave] = m; ss[wave] = s; }
    if (half == 0) *(float4*)&sacc[wave][col4 * 4] = acc;
    __syncthreads();

    if (tid < D) {
        float m0 = sm[0], m1 = sm[1], m2 = sm[2], m3 = sm[3];
        float mstar = fmaxf(fmaxf(m0, m1), fmaxf(m2, m3));
        float r = 0.f;
        if (mstar > -INFINITY) {   // empty segment -> r = 0 (matches reference guard)
            float e0 = __expf(m0 - mstar), e1 = __expf(m1 - mstar);
            float e2 = __expf(m2 - mstar), e3 = __expf(m3 - mstar);
            float stot = ss[0] * e0 + ss[1] * e1 + ss[2] * e2 + ss[3] * e3;
            float at = sacc[0][tid] * e0 + sacc[1][tid] * e1
                     + sacc[2][tid] * e2 + sacc[3][tid] * e3;
            r = at / fmaxf(stot, 1e-16f);
        }
        r_out[(size_t)g * r_stride + tid] = r;
    }
}

// ---------------- gates GEMM: gates[g,j] = bias[j] + A1[g,:]·W1[j,:] + A2[g,:]·W2[j,:]
__global__ __launch_bounds__(256) void gates_gemm_kernel(
    const float* __restrict__ A1,   // [G, D] stride D, or nullptr to skip phase 0
    const float* __restrict__ W1,   // [512, D] stride D (Wc)
    const float* __restrict__ A2,   // [G, D] stride D
    const float* __restrict__ W2,   // [512, .] stride sW2 (W_ih + D, stride 2D)
    int sW2,
    const float* __restrict__ bias, // [512]
    float* __restrict__ gates) {    // [G, 512]
    __shared__ float As[16][132];
    __shared__ float Ws[16][132];
    int t = threadIdx.x;
    int tx = t & 15, ty = t >> 4;
    int g0 = blockIdx.x * 128, j0 = blockIdx.y * 128;
    int lr = t >> 1;
    int lk = (t & 1) * 8;

    float acc[8][8];
#pragma unroll
    for (int i = 0; i < 8; ++i)
#pragma unroll
        for (int j = 0; j < 8; ++j) acc[i][j] = 0.f;

    for (int phase = 0; phase < 2; ++phase) {
        const float* A = phase ? A2 : A1;
        if (A == nullptr) continue;
        const float* W = phase ? W2 : W1;
        int sW = phase ? sW2 : D;
        for (int kk = 0; kk < D; kk += 16) {
            float4 a0 = *(const float4*)&A[(size_t)(g0 + lr) * D + kk + lk];
            float4 a1 = *(const float4*)&A[(size_t)(g0 + lr) * D + kk + lk + 4];
            float4 w0 = *(const float4*)&W[(size_t)(j0 + lr) * sW + kk + lk];
            float4 w1 = *(const float4*)&W[(size_t)(j0 + lr) * sW + kk + lk + 4];
            __syncthreads();
            As[lk + 0][lr] = a0.x; As[lk + 1][lr] = a0.y; As[lk + 2][lr] = a0.z; As[lk + 3][lr] = a0.w;
            As[lk + 4][lr] = a1.x; As[lk + 5][lr] = a1.y; As[lk + 6][lr] = a1.z; As[lk + 7][lr] = a1.w;
            Ws[lk + 0][lr] = w0.x; Ws[lk + 1][lr] = w0.y; Ws[lk + 2][lr] = w0.z; Ws[lk + 3][lr] = w0.w;
            Ws[lk + 4][lr] = w1.x; Ws[lk + 5][lr] = w1.y; Ws[lk + 6][lr] = w1.z; Ws[lk + 7][lr] = w1.w;
            __syncthreads();
#pragma unroll
            for (int k = 0; k < 16; ++k) {
                float4 a0v = *(const float4*)&As[k][ty * 8];
                float4 a1v = *(const float4*)&As[k][ty * 8 + 4];
                float4 b0v = *(const float4*)&Ws[k][tx * 8];
                float4 b1v = *(const float4*)&Ws[k][tx * 8 + 4];
                float av[8] = {a0v.x, a0v.y, a0v.z, a0v.w, a1v.x, a1v.y, a1v.z, a1v.w};
                float bv[8] = {b0v.x, b0v.y, b0v.z, b0v.w, b1v.x, b1v.y, b1v.z, b1v.w};
#pragma unroll
                for (int i = 0; i < 8; ++i)
#pragma unroll
                    for (int j = 0; j < 8; ++j)
                        acc[i][j] = fmaf(av[i], bv[j], acc[i][j]);
            }
        }
    }
#pragma unroll
    for (int i = 0; i < 8; ++i) {
        size_t row = (size_t)(g0 + ty * 8 + i);
        float4 o0, o1;
        int jb = j0 + tx * 8;
        o0.x = acc[i][0] + bias[jb + 0]; o0.y = acc[i][1] + bias[jb + 1];
        o0.z = acc[i][2] + bias[jb + 2]; o0.w = acc[i][3] + bias[jb + 3];
        o1.x = acc[i][4] + bias[jb + 4]; o1.y = acc[i][5] + bias[jb + 5];
        o1.z = acc[i][6] + bias[jb + 6]; o1.w = acc[i][7] + bias[jb + 7];
        *(float4*)&gates[row * 512 + jb] = o0;
        *(float4*)&gates[row * 512 + jb + 4] = o1;
    }
}

// ---------------- LSTM cell elementwise ----------------
__global__ void cell_kernel(const float* __restrict__ gates,
                            const float* __restrict__ c_prev, int c_stride,
                            float* __restrict__ c_out,
                            float* __restrict__ h_out, int h_stride,
                            int total) {
    int t = blockIdx.x * blockDim.x + threadIdx.x;
    if (t >= total) return;
    int g = t >> 7, k = t & (D - 1);
    const float* grow = gates + (size_t)g * 512;
    float ig = grow[k];
    float fg = grow[D + k];
    float gg = grow[2 * D + k];
    float og = grow[3 * D + k];
    float cp = c_prev[(size_t)g * c_stride + k];
    float c = sigmoidf_(fg) * cp + sigmoidf_(ig) * tanhf(gg);
    float h = sigmoidf_(og) * tanhf(c);
    c_out[t] = c;
    h_out[(size_t)g * h_stride + k] = h;
}

extern "C" void kernel_launch(void* const* d_in, const int* in_sizes, int n_in,
                              void* d_out, int out_size, void* d_ws, size_t ws_size,
                              hipStream_t stream) {
    const float* x      = (const float*)d_in[0];
    const float* W_ih   = (const float*)d_in[1];
    const float* W_hh   = (const float*)d_in[2];
    const float* b_ih   = (const float*)d_in[3];
    const float* b_hh   = (const float*)d_in[4];
    const int*   index  = (const int*)d_in[5];
    int N = in_sizes[5];
    int G = out_size / (2 * D);
    float* out = (float*)d_out;

    float* ws = (float*)d_ws;
    float* Wc     = ws;                         // 512*D
    float* b_sum  = Wc + 4 * D * D;             // 512
    float* h1     = b_sum + 4 * D;              // D
    float* c1     = h1 + D;                     // D
    float* base2  = c1 + D;                     // 512
    float* r1     = base2 + 4 * D;              // G*D
    float* h2     = r1 + (size_t)G * D;         // G*D
    float* c2     = h2 + (size_t)G * D;         // G*D
    float* r2     = c2 + (size_t)G * D;         // G*D
    float* gatesb = r2 + (size_t)G * D;         // G*4D
    int* seg_off  = (int*)(gatesb + (size_t)G * 4 * D);
    float* c3     = r1;  // r1 dead after step-3 GEMM; c3 never read

    seg_bounds_kernel<<<(G + 1 + 255) / 256, 256, 0, stream>>>(index, N, G, seg_off);
    prep_wc_kernel<<<(4 * D * D + 255) / 256, 256, 0, stream>>>(W_ih, W_hh, Wc);
    prep_bias_kernel<<<1, 512, 0, stream>>>(b_ih, b_hh, b_sum, h1, c1);
    base2_kernel<<<2, 256, 0, stream>>>(Wc, b_sum, h1, base2);

    // ---- step 1: h1/c1 constant row; attention with broadcast q = h1
    attn_kernel<<<G, 256, 0, stream>>>(x, seg_off, h1, 0, r1, D, G);

    // ---- step 2
    gates_gemm_kernel<<<dim3(G / 128, 4), 256, 0, stream>>>(
        nullptr, Wc, r1, W_ih + D, 2 * D, base2, gatesb);
    cell_kernel<<<(G * D + 255) / 256, 256, 0, stream>>>(gatesb, c1, 0, c2, h2, D, G * D);
    attn_kernel<<<G, 256, 0, stream>>>(x, seg_off, h2, D, r2, D, G);

    // ---- step 3
    gates_gemm_kernel<<<dim3(G / 128, 4), 256, 0, stream>>>(
        h2, Wc, r2, W_ih + D, 2 * D, b_sum, gatesb);
    cell_kernel<<<(G * D + 255) / 256, 256, 0, stream>>>(gatesb, c2, D, c3, out, 2 * D, G * D);
    attn_kernel<<<G, 256, 0, stream>>>(x, seg_off, out, 2 * D, out + D, 2 * D, G);
}